// Round 1
// baseline (1059.325 us; speedup 1.0000x reference)
//
#include <hip/hip_runtime.h>
#include <math.h>

// Problem constants
// B=8, L=8192, W=128, MODES=32, NL=4, SEG=4 (seglen 2048), CM=8, H1=128

// ---------------- workspace layout (in floats) ----------------
#define OFF_COSTAB 0
#define OFF_SINTAB 8192
#define OFF_BASIS  16384                         // [8192][64]  (cols 0..31 cos, 32..63 sin)
#define OFF_FC1T   (OFF_BASIS + 8192*64)         // [128][128]  fc1_w transposed [h1][c]
#define OFF_WBAR   (OFF_FC1T + 128*128)          // [NL][SEG][CM][W]
#define OFF_HFP    (OFF_WBAR + 4*4*8*128)        // [16][1024][64] DFT partials
#define OFF_HF     (OFF_HFP + 16*1024*64)        // [1024][64]
#define OFF_CH     (OFF_HF + 1024*64)            // [1024][4][8] cheb coeffs
#define OFF_REC    (OFF_CH + 1024*32)            // [8*128][4]
#define OFF_OMC    (OFF_REC + 8*128*4)           // [8][128][32]
#define OFF_OMS    (OFF_OMC + 8*128*32)          // [8][128][32]
#define OFF_CG     (OFF_OMS + 8*128*32)          // [8][4][128]
#define OFF_MNMX   (OFF_CG + 8*4*128)            // 8 uints (4 min enc, 4 max enc)
#define OFF_H      (OFF_MNMX + 16)               // [8][128][8192]

__device__ __forceinline__ unsigned int enc_f(float f) {
    unsigned int u = __float_as_uint(f);
    return (u & 0x80000000u) ? ~u : (u | 0x80000000u);
}
__device__ __forceinline__ float dec_f(unsigned int u) {
    return (u & 0x80000000u) ? __uint_as_float(u ^ 0x80000000u) : __uint_as_float(~u);
}
__device__ __forceinline__ float gelu_f(float x) {
    return 0.5f * x * (1.0f + erff(x * 0.70710678118654752f));
}
__device__ __forceinline__ float sigmoid_f(float x) {
    return 1.0f / (1.0f + expf(-x));
}

// ---------------- init kernels ----------------
__global__ void k_tab(float* ws) {
    int m = blockIdx.x * 256 + threadIdx.x;
    if (m < 8192) {
        double a = (double)m * (6.283185307179586476925286766559 / 8192.0);
        ws[OFF_COSTAB + m] = (float)cos(a);
        ws[OFF_SINTAB + m] = (float)sin(a);
    }
}

__global__ void k_init2(float* ws, const float* __restrict__ fc1_w,
                        const float* __restrict__ cheb_w) {
    int tid = blockIdx.x * 256 + threadIdx.x;
    if (tid < 524288) {
        int l = tid >> 6, j = tid & 63;
        int k = j & 31;
        int tab = (j < 32) ? OFF_COSTAB : OFF_SINTAB;
        ws[OFF_BASIS + tid] = ws[tab + ((k * l) & 8191)];
    } else if (tid < 524288 + 16384) {
        int r = tid - 524288;
        int h1 = r >> 7, c = r & 127;
        ws[OFF_FC1T + r] = fc1_w[c * 128 + h1];
    } else if (tid < 524288 + 32768) {
        int r = tid - (524288 + 16384);   // r = ((layer*4+s)*8+m)*128 + c
        int c = r & 127;
        int smi = r >> 7;                 // (layer*4+s)*8+m
        const float* wp = cheb_w + ((long)smi * 128 + c) * 128;
        float s = 0.0f;
        for (int o = 0; o < 128; o++) s += wp[o];
        ws[OFF_WBAR + r] = s * (1.0f / 128.0f);
    } else if (tid < 524288 + 32768 + 8) {
        int r = tid - (524288 + 32768);
        unsigned int* mm = (unsigned int*)(ws + OFF_MNMX);
        mm[r] = (r < 4) ? 0xFFFFFFFFu : 0u;
    }
}

// ---------------- fc0: h[b][c][l] = x@fc0_w + b, plus seg min/max ----------------
__global__ __launch_bounds__(256) void k_fc0(float* ws, const float* __restrict__ x,
                                             const float* __restrict__ w,
                                             const float* __restrict__ bias) {
    int bid = blockIdx.x;
    int b = bid >> 5;
    int l0 = (bid & 31) * 256;
    int t = threadIdx.x;
    int l = l0 + t;
    float x0 = x[((long)b * 8192 + l) * 2];
    float x1 = x[((long)b * 8192 + l) * 2 + 1];
    float* hb = ws + OFF_H + (long)b * 128 * 8192;
    float mn = 1e30f, mx = -1e30f;
    for (int c = 0; c < 128; c++) {
        float v = fmaf(x0, w[c], fmaf(x1, w[128 + c], bias[c]));
        hb[(long)c * 8192 + l] = v;
        mn = fminf(mn, v); mx = fmaxf(mx, v);
    }
    for (int off = 32; off; off >>= 1) {
        mn = fminf(mn, __shfl_down(mn, off));
        mx = fmaxf(mx, __shfl_down(mx, off));
    }
    __shared__ float rmn[4], rmx[4];
    if ((t & 63) == 0) { rmn[t >> 6] = mn; rmx[t >> 6] = mx; }
    __syncthreads();
    if (t == 0) {
        for (int w2 = 1; w2 < 4; w2++) { mn = fminf(mn, rmn[w2]); mx = fmaxf(mx, rmx[w2]); }
        unsigned int* mm = (unsigned int*)(ws + OFF_MNMX);
        int seg = l0 >> 11;
        atomicMin(&mm[seg], enc_f(mn));
        atomicMax(&mm[4 + seg], enc_f(mx));
    }
}

// ---------------- forward DFT (32 modes): GEMM h[1024x8192] @ basis[8192x64] ----------------
__global__ __launch_bounds__(256) void k_dft(float* ws) {
    __shared__ float As[64 * 68];
    __shared__ float Bs[64 * 68];
    int rt = blockIdx.x, kc = blockIdx.y, t = threadIdx.x;
    int r0 = rt * 64, lb0 = kc * 512;
    int tr = t >> 4, tcol = t & 15;
    float acc[4][4] = {};
    const float* h = ws + OFF_H;
    const float* basis = ws + OFF_BASIS;
    for (int kk = 0; kk < 8; kk++) {
        int lbase = lb0 + kk * 64;
        #pragma unroll
        for (int i = 0; i < 4; i++) {
            int idx = t + i * 256;
            int row = idx >> 4, c4 = (idx & 15) * 4;
            *(float4*)&As[row * 68 + c4] = *(const float4*)&h[(long)(r0 + row) * 8192 + lbase + c4];
            *(float4*)&Bs[row * 68 + c4] = *(const float4*)&basis[(long)(lbase + row) * 64 + c4];
        }
        __syncthreads();
        #pragma unroll 8
        for (int l = 0; l < 64; l++) {
            float4 bv = *(const float4*)&Bs[l * 68 + tcol * 4];
            #pragma unroll
            for (int i = 0; i < 4; i++) {
                float av = As[(tr * 4 + i) * 68 + l];
                acc[i][0] = fmaf(av, bv.x, acc[i][0]);
                acc[i][1] = fmaf(av, bv.y, acc[i][1]);
                acc[i][2] = fmaf(av, bv.z, acc[i][2]);
                acc[i][3] = fmaf(av, bv.w, acc[i][3]);
            }
        }
        __syncthreads();
    }
    float* hfp = ws + OFF_HFP + (long)kc * 65536;
    #pragma unroll
    for (int i = 0; i < 4; i++)
        #pragma unroll
        for (int j = 0; j < 4; j++)
            hfp[(long)(r0 + tr * 4 + i) * 64 + tcol * 4 + j] = acc[i][j];
}

// ---------------- Chebyshev coefficients C[row][s][m] ----------------
__global__ __launch_bounds__(256) void k_cheb(float* ws) {
    int row = blockIdx.x, t = threadIdx.x;
    const float* hr = ws + OFF_H + (long)row * 8192;
    const unsigned int* mm = (const unsigned int*)(ws + OFF_MNMX);
    __shared__ float red[4][8];
    for (int s = 0; s < 4; s++) {
        float mn = dec_f(mm[s]), mx = dec_f(mm[4 + s]);
        float sc = 2.0f / (mx - mn);
        float acc[8] = {};
        for (int j = 0; j < 8; j++) {
            float x = hr[s * 2048 + t + j * 256];
            float xn = (x - mn) * sc - 1.0f;
            float tpp = 1.0f, tp = xn;
            acc[0] += xn;
            acc[1] += xn * xn;
            #pragma unroll
            for (int m = 2; m < 8; m++) {
                float tn = 2.0f * xn * tp - tpp;
                acc[m] += xn * tn;
                tpp = tp; tp = tn;
            }
        }
        for (int off = 32; off; off >>= 1)
            #pragma unroll
            for (int m = 0; m < 8; m++) acc[m] += __shfl_down(acc[m], off);
        if ((t & 63) == 0)
            for (int m = 0; m < 8; m++) red[t >> 6][m] = acc[m];
        __syncthreads();
        if (t < 8) {
            float tot = red[0][t] + red[1][t] + red[2][t] + red[3][t];
            ws[OFF_CH + (long)row * 32 + s * 8 + t] = tot * (1.0f / 2048.0f);
        }
        __syncthreads();
    }
}

// ---------------- B1: reduce DFT partials; rec = tanh(C . wbar) ----------------
__global__ void k_b1(float* ws, int layer) {
    int tid = blockIdx.x * 256 + threadIdx.x;
    if (tid < 65536) {
        float s = 0.0f;
        for (int p = 0; p < 16; p++) s += ws[OFF_HFP + (long)p * 65536 + tid];
        ws[OFF_HF + tid] = s;
    } else if (tid < 65536 + 4096) {
        int r = tid - 65536;
        int bc = r >> 2, s = r & 3;
        int c = bc & 127;
        const float* Cp = ws + OFF_CH + (long)bc * 32 + s * 8;
        const float* wb = ws + OFF_WBAR + ((layer * 4 + s) * 8) * 128 + c;
        float a = 0.0f;
        #pragma unroll
        for (int m = 0; m < 8; m++) a = fmaf(Cp[m], wb[m * 128], a);
        ws[OFF_REC + (long)bc * 4 + s] = tanhf(a);
    }
}

// ---------------- B2: mode mix -> omc/oms; cgate; reset minmax slots ----------------
__global__ void k_b2(float* ws, const float* __restrict__ swr, const float* __restrict__ swi,
                     const float* __restrict__ gw, const float* __restrict__ gb, int layer) {
    int tid = blockIdx.x * 256 + threadIdx.x;
    if (tid < 32768) {
        int b = tid >> 12, o = (tid >> 5) & 127, k = tid & 31;
        const float* hfb = ws + OFF_HF + (long)b * 8192;  // [128][64]
        const float* wr = swr + (long)layer * 524288 + (long)o * 32 + k;
        const float* wi = swi + (long)layer * 524288 + (long)o * 32 + k;
        float omr = 0.0f, omi = 0.0f;
        for (int i = 0; i < 128; i++) {
            float hr = hfb[i * 64 + k];
            float hs = hfb[i * 64 + 32 + k];
            float wrv = wr[(long)i * 4096], wiv = wi[(long)i * 4096];
            omr = fmaf(hr, wrv, fmaf(hs, wiv, omr));
            omi = fmaf(hr, wiv, fmaf(-hs, wrv, omi));
        }
        float ck = (k == 0) ? (1.0f / 8192.0f) : (2.0f / 8192.0f);
        ws[OFF_OMC + tid] = ck * omr;
        ws[OFF_OMS + tid] = -ck * omi;
    } else if (tid < 32768 + 4096) {
        int r = tid - 32768;
        int b = r >> 9, s = (r >> 7) & 3, o = r & 127;
        float a = gb[layer * 128 + o];
        const float* recp = ws + OFF_REC + (long)b * 512 + s;
        const float* g2 = gw + (long)layer * 32768 + 16384 + o;
        for (int c = 0; c < 128; c++) a = fmaf(recp[c * 4], g2[c * 128], a);
        ws[OFF_CG + (long)(b * 4 + s) * 128 + o] = a;
    }
    if (blockIdx.x == gridDim.x - 1 && threadIdx.x < 8) {
        unsigned int* mm = (unsigned int*)(ws + OFF_MNMX);
        mm[threadIdx.x] = (threadIdx.x < 4) ? 0xFFFFFFFFu : 0u;
    }
}

// ---------------- fused layer core: irfft + conv + gelu + gate + update (in place) ----------------
__global__ __launch_bounds__(256) void k_fuse(float* ws, const float* __restrict__ cw,
                                              const float* __restrict__ cb,
                                              const float* __restrict__ gw, int layer) {
    __shared__ float hT[128 * 36];
    __shared__ float xf[128 * 36];
    __shared__ float omL[128 * 64];
    __shared__ float basL[32 * 68];
    __shared__ float rmn[4], rmx[4];
    int bid = blockIdx.x;
    int b = bid >> 8;
    int tile = bid & 255;
    int l0 = tile * 32;
    int seg = tile >> 6;
    int t = threadIdx.x;
    float* hb = ws + OFF_H + (long)b * 128 * 8192;

    #pragma unroll
    for (int i = 0; i < 4; i++) {
        int idx = t + i * 256;
        int row = idx >> 3, c4 = (idx & 7) * 4;
        *(float4*)&hT[row * 36 + c4] = *(const float4*)&hb[(long)row * 8192 + l0 + c4];
    }
    #pragma unroll
    for (int i = 0; i < 4; i++) {
        int idx = t + i * 256;
        int o = idx >> 3, k4 = (idx & 7) * 4;
        *(float4*)&omL[o * 64 + k4]      = *(const float4*)&ws[OFF_OMC + (long)(b * 128 + o) * 32 + k4];
        *(float4*)&omL[o * 64 + 32 + k4] = *(const float4*)&ws[OFF_OMS + (long)(b * 128 + o) * 32 + k4];
    }
    #pragma unroll
    for (int i = 0; i < 2; i++) {
        int idx = t + i * 256;
        int r = idx >> 4, j4 = (idx & 15) * 4;
        *(float4*)&basL[r * 68 + j4] = *(const float4*)&ws[OFF_BASIS + (long)(l0 + r) * 64 + j4];
    }
    __syncthreads();

    int c0 = (t >> 4) * 8;
    int lb = (t & 15) * 2;
    float acc0[8] = {}, acc1[8] = {};

    // inverse DFT (32 modes)
    for (int k = 0; k < 32; k++) {
        float cv0 = basL[lb * 68 + k],       sv0 = basL[lb * 68 + 32 + k];
        float cv1 = basL[(lb + 1) * 68 + k], sv1 = basL[(lb + 1) * 68 + 32 + k];
        #pragma unroll
        for (int i = 0; i < 8; i++) {
            float oc = omL[(c0 + i) * 64 + k];
            float os = omL[(c0 + i) * 64 + 32 + k];
            acc0[i] = fmaf(oc, cv0, fmaf(os, sv0, acc0[i]));
            acc1[i] = fmaf(oc, cv1, fmaf(os, sv1, acc1[i]));
        }
    }
    // 1x1 conv bypass
    const float* cwl = cw + (long)layer * 16384;
    for (int j = 0; j < 128; j++) {
        float h0 = hT[j * 36 + lb], h1 = hT[j * 36 + lb + 1];
        float4 wa = *(const float4*)&cwl[j * 128 + c0];
        float4 wb = *(const float4*)&cwl[j * 128 + c0 + 4];
        float wv[8] = {wa.x, wa.y, wa.z, wa.w, wb.x, wb.y, wb.z, wb.w};
        #pragma unroll
        for (int i = 0; i < 8; i++) {
            acc0[i] = fmaf(h0, wv[i], acc0[i]);
            acc1[i] = fmaf(h1, wv[i], acc1[i]);
        }
    }
    #pragma unroll
    for (int i = 0; i < 8; i++) {
        float bias = cb[layer * 128 + c0 + i];
        xf[(c0 + i) * 36 + lb]     = gelu_f(acc0[i] + bias);
        xf[(c0 + i) * 36 + lb + 1] = gelu_f(acc1[i] + bias);
    }
    __syncthreads();

    // gate GEMM over x_fno
    const float* gwl = gw + (long)layer * 32768;
    float g0[8] = {}, g1[8] = {};
    for (int c = 0; c < 128; c++) {
        float x0 = xf[c * 36 + lb], x1 = xf[c * 36 + lb + 1];
        float4 wa = *(const float4*)&gwl[c * 128 + c0];
        float4 wb = *(const float4*)&gwl[c * 128 + c0 + 4];
        float wv[8] = {wa.x, wa.y, wa.z, wa.w, wb.x, wb.y, wb.z, wb.w};
        #pragma unroll
        for (int i = 0; i < 8; i++) {
            g0[i] = fmaf(x0, wv[i], g0[i]);
            g1[i] = fmaf(x1, wv[i], g1[i]);
        }
    }
    float mnv = 1e30f, mxv = -1e30f;
    #pragma unroll
    for (int i = 0; i < 8; i++) {
        int o = c0 + i;
        float cgv = ws[OFF_CG + (long)(b * 4 + seg) * 128 + o];
        float rv = ws[OFF_REC + (long)(b * 128 + o) * 4 + seg];
        float gg0 = sigmoid_f(g0[i] + cgv);
        float gg1 = sigmoid_f(g1[i] + cgv);
        float v0 = xf[o * 36 + lb] + gg0 * rv;
        float v1 = xf[o * 36 + lb + 1] + gg1 * rv;
        hb[(long)o * 8192 + l0 + lb]     = v0;
        hb[(long)o * 8192 + l0 + lb + 1] = v1;
        mnv = fminf(mnv, fminf(v0, v1));
        mxv = fmaxf(mxv, fmaxf(v0, v1));
    }
    for (int off = 32; off; off >>= 1) {
        mnv = fminf(mnv, __shfl_down(mnv, off));
        mxv = fmaxf(mxv, __shfl_down(mxv, off));
    }
    if ((t & 63) == 0) { rmn[t >> 6] = mnv; rmx[t >> 6] = mxv; }
    __syncthreads();
    if (t == 0) {
        for (int w2 = 1; w2 < 4; w2++) { mnv = fminf(mnv, rmn[w2]); mxv = fmaxf(mxv, rmx[w2]); }
        unsigned int* mm = (unsigned int*)(ws + OFF_MNMX);
        atomicMin(&mm[seg], enc_f(mnv));
        atomicMax(&mm[4 + seg], enc_f(mxv));
    }
}

// ---------------- final fc1 (gelu) + fc2 ----------------
__global__ __launch_bounds__(256) void k_fc12(float* ws, const float* __restrict__ f1b,
                                              const float* __restrict__ f2w,
                                              const float* __restrict__ f2b,
                                              float* __restrict__ out) {
    __shared__ float hT[128 * 68];
    __shared__ float red[4][64];
    int bid = blockIdx.x;
    int b = bid >> 7;
    int l0 = (bid & 127) * 64;
    int t = threadIdx.x;
    const float* hb = ws + OFF_H + (long)b * 128 * 8192;
    #pragma unroll
    for (int i = 0; i < 8; i++) {
        int idx = t + i * 256;
        int row = idx >> 4, c4 = (idx & 15) * 4;
        *(float4*)&hT[row * 68 + c4] = *(const float4*)&hb[(long)row * 8192 + l0 + c4];
    }
    __syncthreads();
    int l = t & 63, part = t >> 6;
    const float* f1 = ws + OFF_FC1T + part * 32 * 128;
    float acc = 0.0f;
    for (int h1 = 0; h1 < 32; h1++) {
        float a = f1b[part * 32 + h1];
        const float* f1r = f1 + h1 * 128;
        for (int c = 0; c < 128; c++) a = fmaf(hT[c * 68 + l], f1r[c], a);
        acc = fmaf(f2w[part * 32 + h1], gelu_f(a), acc);
    }
    red[part][l] = acc;
    __syncthreads();
    if (t < 64) {
        float s = red[0][t] + red[1][t] + red[2][t] + red[3][t] + f2b[0];
        out[(long)b * 8192 + l0 + t] = s;
    }
}

extern "C" void kernel_launch(void* const* d_in, const int* in_sizes, int n_in,
                              void* d_out, int out_size, void* d_ws, size_t ws_size,
                              hipStream_t stream) {
    const float* x     = (const float*)d_in[0];
    const float* fc0_w = (const float*)d_in[1];
    const float* fc0_b = (const float*)d_in[2];
    const float* swr   = (const float*)d_in[3];
    const float* swi   = (const float*)d_in[4];
    const float* cw    = (const float*)d_in[5];
    const float* cb    = (const float*)d_in[6];
    const float* chw   = (const float*)d_in[7];
    const float* gw    = (const float*)d_in[8];
    const float* gb    = (const float*)d_in[9];
    const float* f1w   = (const float*)d_in[10];
    const float* f1b   = (const float*)d_in[11];
    const float* f2w   = (const float*)d_in[12];
    const float* f2b   = (const float*)d_in[13];
    float* ws = (float*)d_ws;
    float* out = (float*)d_out;

    k_tab<<<32, 256, 0, stream>>>(ws);
    k_init2<<<2177, 256, 0, stream>>>(ws, f1w, chw);
    k_fc0<<<256, 256, 0, stream>>>(ws, x, fc0_w, fc0_b);
    for (int layer = 0; layer < 4; layer++) {
        k_dft<<<dim3(16, 16), 256, 0, stream>>>(ws);
        k_cheb<<<1024, 256, 0, stream>>>(ws);
        k_b1<<<272, 256, 0, stream>>>(ws, layer);
        k_b2<<<144, 256, 0, stream>>>(ws, swr, swi, gw, gb, layer);
        k_fuse<<<2048, 256, 0, stream>>>(ws, cw, cb, gw, layer);
    }
    k_fc12<<<1024, 256, 0, stream>>>(ws, f1b, f2w, f2b, out);
}

// Round 3
// 788.110 us; speedup vs baseline: 1.3441x; 1.3441x over previous
//
#include <hip/hip_runtime.h>
#include <math.h>

// B=8, L=8192, W=128, MODES=32, NL=4, SEG=4 (seglen 2048), CM=8, H1=128

// ---------------- workspace layout (in floats) ----------------
#define OFF_COSTAB 0
#define OFF_SINTAB 8192
#define OFF_BASTC  16384                     // [32][8192]  cos(2*pi*k*l/L)
#define OFF_BASTS  (OFF_BASTC + 262144)      // [32][8192]  sin  (contiguous -> [64][8192])
#define OFF_UNUSED (OFF_BASTS + 262144)      // (was CWT; conv_w is read directly now)
#define OFF_WBAR   (OFF_UNUSED + 65536)      // [NL][SEG][CM][W]
#define OFF_HFP    (OFF_WBAR + 16384)        // [16][1024][64] DFT partials
#define OFF_HF     (OFF_HFP + 1048576)       // [1024][64]
#define OFF_CH     (OFF_HF + 65536)          // [1024][4][8]
#define OFF_REC    (OFF_CH + 32768)          // [8*128][4]
#define OFF_OMCT   (OFF_REC + 4096)          // [8][32 k][128 o]
#define OFF_OMST   (OFF_OMCT + 32768)        // [8][32 k][128 o]
#define OFF_CG     (OFF_OMST + 32768)        // [8][4][128]
#define OFF_MNMX   (OFF_CG + 4096)           // 8 uints
#define OFF_H      (OFF_MNMX + 16)           // [8][128][8192]

__device__ __forceinline__ unsigned int enc_f(float f) {
    unsigned int u = __float_as_uint(f);
    return (u & 0x80000000u) ? ~u : (u | 0x80000000u);
}
__device__ __forceinline__ float dec_f(unsigned int u) {
    return (u & 0x80000000u) ? __uint_as_float(u ^ 0x80000000u) : __uint_as_float(~u);
}
__device__ __forceinline__ float gelu_f(float x) {
    return 0.5f * x * (1.0f + erff(x * 0.70710678118654752f));
}
__device__ __forceinline__ float sigmoid_f(float x) {
    return 1.0f / (1.0f + expf(-x));
}

// ---------------- init ----------------
__global__ void k_tab(float* ws) {
    int m = blockIdx.x * 256 + threadIdx.x;
    if (m < 8192) {
        double a = (double)m * (6.283185307179586476925286766559 / 8192.0);
        ws[OFF_COSTAB + m] = (float)cos(a);
        ws[OFF_SINTAB + m] = (float)sin(a);
    }
}

__global__ void k_init2(float* ws, const float* __restrict__ cheb_w) {
    int tid = blockIdx.x * 256 + threadIdx.x;
    if (tid < 524288) {
        // basT [64][8192]: rows 0..31 cos, 32..63 sin
        int j = tid >> 13, l = tid & 8191;
        int k = j & 31;
        int tab = (j < 32) ? OFF_COSTAB : OFF_SINTAB;
        ws[OFF_BASTC + tid] = ws[tab + ((k * l) & 8191)];
    } else if (tid < 524288 + 16384) {
        int r = tid - 524288;           // ((layer*4+s)*8+m)*128 + c
        int c = r & 127;
        int smi = r >> 7;
        const float* wp = cheb_w + ((long)smi * 128 + c) * 128;
        float s = 0.0f;
        for (int o = 0; o < 128; o++) s += wp[o];
        ws[OFF_WBAR + r] = s * (1.0f / 128.0f);
    } else if (tid < 524288 + 16384 + 8) {
        int r = tid - (524288 + 16384);
        unsigned int* mm = (unsigned int*)(ws + OFF_MNMX);
        mm[r] = (r < 4) ? 0xFFFFFFFFu : 0u;
    }
}

// ---------------- fc0 + seg min/max ----------------
__global__ __launch_bounds__(256) void k_fc0(float* ws, const float* __restrict__ x,
                                             const float* __restrict__ w,
                                             const float* __restrict__ bias) {
    int bid = blockIdx.x;
    int b = bid >> 5;
    int l0 = (bid & 31) * 256;
    int t = threadIdx.x;
    int l = l0 + t;
    float x0 = x[((long)b * 8192 + l) * 2];
    float x1 = x[((long)b * 8192 + l) * 2 + 1];
    float* hb = ws + OFF_H + (long)b * 128 * 8192;
    float mn = 1e30f, mx = -1e30f;
    for (int c = 0; c < 128; c++) {
        float v = fmaf(x0, w[c], fmaf(x1, w[128 + c], bias[c]));
        hb[(long)c * 8192 + l] = v;
        mn = fminf(mn, v); mx = fmaxf(mx, v);
    }
    for (int off = 32; off; off >>= 1) {
        mn = fminf(mn, __shfl_down(mn, off));
        mx = fmaxf(mx, __shfl_down(mx, off));
    }
    __shared__ float rmn[4], rmx[4];
    if ((t & 63) == 0) { rmn[t >> 6] = mn; rmx[t >> 6] = mx; }
    __syncthreads();
    if (t == 0) {
        for (int w2 = 1; w2 < 4; w2++) { mn = fminf(mn, rmn[w2]); mx = fmaxf(mx, rmx[w2]); }
        unsigned int* mm = (unsigned int*)(ws + OFF_MNMX);
        int seg = l0 >> 11;
        atomicMin(&mm[seg], enc_f(mn));
        atomicMax(&mm[4 + seg], enc_f(mx));
    }
}

// ---------------- forward DFT: h[1024x8192] @ basT^T[8192x64], K-split 16 ----------------
// Double-buffered LDS, both tiles stored transposed with XOR swizzle (idx ^ (l&28))
// so staging writes and compute-loop reads are conflict-free; reads are ds_read_b128.
__global__ __launch_bounds__(256) void k_dft(float* ws) {
    __shared__ float AsT[2][64 * 68];  // [l][row ^ swz]
    __shared__ float Bs[2][64 * 68];   // [l][col ^ swz]
    int rt = blockIdx.x, kc = blockIdx.y, t = threadIdx.x;
    int r0 = rt * 64, lb0 = kc * 512;
    int tr = t >> 4, tc = t & 15;
    const float* h = ws + OFF_H;
    const float* basT = ws + OFF_BASTC;  // [64][8192]
    int sr = t >> 4;            // staging base row/col (0..15), +16*i
    int sc4 = (t & 15) * 4;     // staging l4 within chunk
    int xsw = sc4 & 28;
    float4 pa[4], pb[4];

    auto LOADT = [&](int kk) {
        int lb = lb0 + kk * 64;
        #pragma unroll
        for (int i = 0; i < 4; i++) {
            pa[i] = *(const float4*)&h[(long)(r0 + sr + 16 * i) * 8192 + lb + sc4];
            pb[i] = *(const float4*)&basT[(long)(sr + 16 * i) * 8192 + lb + sc4];
        }
    };
    auto STORET = [&](float* A, float* Bb) {
        #pragma unroll
        for (int i = 0; i < 4; i++) {
            int rw = (sr + 16 * i) ^ xsw;
            float va[4] = {pa[i].x, pa[i].y, pa[i].z, pa[i].w};
            float vb[4] = {pb[i].x, pb[i].y, pb[i].z, pb[i].w};
            #pragma unroll
            for (int q = 0; q < 4; q++) {
                A[(sc4 + q) * 68 + rw] = va[q];
                Bb[(sc4 + q) * 68 + rw] = vb[q];
            }
        }
    };

    float acc[4][4] = {};
    LOADT(0);
    for (int kk = 0; kk < 8; kk++) {
        int bi = kk & 1;
        STORET(&AsT[bi][0], &Bs[bi][0]);
        __syncthreads();
        if (kk < 7) LOADT(kk + 1);
        float* Ab = &AsT[bi][0];
        float* Bb = &Bs[bi][0];
        #pragma unroll 8
        for (int l = 0; l < 64; l++) {
            int sw = l & 28;
            float4 av = *(const float4*)&Ab[l * 68 + ((tr * 4) ^ sw)];
            float4 bv = *(const float4*)&Bb[l * 68 + ((tc * 4) ^ sw)];
            float aa[4] = {av.x, av.y, av.z, av.w};
            #pragma unroll
            for (int i = 0; i < 4; i++) {
                acc[i][0] = fmaf(aa[i], bv.x, acc[i][0]);
                acc[i][1] = fmaf(aa[i], bv.y, acc[i][1]);
                acc[i][2] = fmaf(aa[i], bv.z, acc[i][2]);
                acc[i][3] = fmaf(aa[i], bv.w, acc[i][3]);
            }
        }
        __syncthreads();
    }
    float* hfp = ws + OFF_HFP + (long)kc * 65536;
    #pragma unroll
    for (int i = 0; i < 4; i++)
        #pragma unroll
        for (int j = 0; j < 4; j++)
            hfp[(long)(r0 + tr * 4 + i) * 64 + tc * 4 + j] = acc[i][j];
}

// ---------------- Chebyshev coefficients ----------------
__global__ __launch_bounds__(256) void k_cheb(float* ws) {
    int row = blockIdx.x, t = threadIdx.x;
    const float* hr = ws + OFF_H + (long)row * 8192;
    const unsigned int* mm = (const unsigned int*)(ws + OFF_MNMX);
    __shared__ float red[4][8];
    for (int s = 0; s < 4; s++) {
        float mn = dec_f(mm[s]), mx = dec_f(mm[4 + s]);
        float sc = 2.0f / (mx - mn);
        float acc[8] = {};
        float4 va = *(const float4*)&hr[s * 2048 + t * 8];
        float4 vb = *(const float4*)&hr[s * 2048 + t * 8 + 4];
        float xsv[8] = {va.x, va.y, va.z, va.w, vb.x, vb.y, vb.z, vb.w};
        #pragma unroll
        for (int e = 0; e < 8; e++) {
            float xn = (xsv[e] - mn) * sc - 1.0f;
            float tpp = 1.0f, tp = xn;
            acc[0] += xn;
            acc[1] += xn * xn;
            #pragma unroll
            for (int mI = 2; mI < 8; mI++) {
                float tn = 2.0f * xn * tp - tpp;
                acc[mI] += xn * tn;
                tpp = tp; tp = tn;
            }
        }
        for (int off = 32; off; off >>= 1)
            #pragma unroll
            for (int mI = 0; mI < 8; mI++) acc[mI] += __shfl_down(acc[mI], off);
        if ((t & 63) == 0)
            for (int mI = 0; mI < 8; mI++) red[t >> 6][mI] = acc[mI];
        __syncthreads();
        if (t < 8) {
            float tot = red[0][t] + red[1][t] + red[2][t] + red[3][t];
            ws[OFF_CH + (long)row * 32 + s * 8 + t] = tot * (1.0f / 2048.0f);
        }
        __syncthreads();
    }
}

// ---------------- B1: reduce DFT partials; rec = tanh(C . wbar) ----------------
__global__ void k_b1(float* ws, int layer) {
    int tid = blockIdx.x * 256 + threadIdx.x;
    if (tid < 65536) {
        float s = 0.0f;
        for (int p = 0; p < 16; p++) s += ws[OFF_HFP + (long)p * 65536 + tid];
        ws[OFF_HF + tid] = s;
    } else if (tid < 65536 + 4096) {
        int r = tid - 65536;
        int bc = r >> 2, s = r & 3;
        int c = bc & 127;
        const float* Cp = ws + OFF_CH + (long)bc * 32 + s * 8;
        const float* wb = ws + OFF_WBAR + ((layer * 4 + s) * 8) * 128 + c;
        float a = 0.0f;
        #pragma unroll
        for (int m = 0; m < 8; m++) a = fmaf(Cp[m], wb[m * 128], a);
        ws[OFF_REC + (long)bc * 4 + s] = tanhf(a);
    }
}

// ---------------- B2: mode mix -> omT (k-major); cgate; reset minmax ----------------
__global__ void k_b2(float* ws, const float* __restrict__ swr, const float* __restrict__ swi,
                     const float* __restrict__ gw, const float* __restrict__ gb, int layer) {
    int tid = blockIdx.x * 256 + threadIdx.x;
    if (tid < 32768) {
        int b = tid >> 12, o = (tid >> 5) & 127, k = tid & 31;
        const float* hfb = ws + OFF_HF + (long)b * 8192;  // [128][64]
        const float* wr = swr + (long)layer * 524288 + (long)o * 32 + k;
        const float* wi = swi + (long)layer * 524288 + (long)o * 32 + k;
        float omr = 0.0f, omi = 0.0f;
        for (int i = 0; i < 128; i++) {
            float hr = hfb[i * 64 + k];
            float hs = hfb[i * 64 + 32 + k];
            float wrv = wr[(long)i * 4096], wiv = wi[(long)i * 4096];
            omr = fmaf(hr, wrv, fmaf(hs, wiv, omr));
            omi = fmaf(hr, wiv, fmaf(-hs, wrv, omi));
        }
        float ck = (k == 0) ? (1.0f / 8192.0f) : (2.0f / 8192.0f);
        ws[OFF_OMCT + ((long)b * 32 + k) * 128 + o] = ck * omr;
        ws[OFF_OMST + ((long)b * 32 + k) * 128 + o] = -ck * omi;
    } else if (tid < 32768 + 4096) {
        int r = tid - 32768;
        int b = r >> 9, s = (r >> 7) & 3, o = r & 127;
        float a = gb[layer * 128 + o];
        const float* recp = ws + OFF_REC + (long)b * 512 + s;
        const float* g2 = gw + (long)layer * 32768 + 16384 + o;
        for (int c = 0; c < 128; c++) a = fmaf(recp[c * 4], g2[c * 128], a);
        ws[OFF_CG + (long)(b * 4 + s) * 128 + o] = a;
    }
    if (blockIdx.x == gridDim.x - 1 && threadIdx.x < 8) {
        unsigned int* mm = (unsigned int*)(ws + OFF_MNMX);
        mm[threadIdx.x] = (threadIdx.x < 4) ? 0xFFFFFFFFu : 0u;
    }
}

// ---------------- fused layer: irfft + conv + gelu + gate + update (in place) ----------------
// 64-pos tile, one 128x68 LDS buffer (h, reused for x_fno). omT/basT/conv_w/gw from L1.
// conv_w is [layer][i][o] row-major = exactly the K-major layout the inner loop wants.
__global__ __launch_bounds__(256, 4) void k_fuse(float* ws, const float* __restrict__ cw,
                                                 const float* __restrict__ cb,
                                                 const float* __restrict__ gw, int layer) {
    __shared__ float hx[128 * 68];
    __shared__ float rmn[4], rmx[4];
    int bid = blockIdx.x;
    int b = bid >> 7;
    int tile = bid & 127;
    int l0 = tile * 64;
    int seg = l0 >> 11;
    int t = threadIdx.x;
    float* hb = ws + OFF_H + (long)b * 1048576;

    #pragma unroll
    for (int i = 0; i < 8; i++) {
        int idx = t + i * 256;
        int row = idx >> 4, c4 = (idx & 15) * 4;
        *(float4*)&hx[row * 68 + c4] = *(const float4*)&hb[(long)row * 8192 + l0 + c4];
    }
    __syncthreads();

    int g = t >> 4, m = t & 15;
    int c0 = g * 8, p0 = m * 4;
    float acc[8][4] = {};

    // inverse DFT (32 modes)
    const float* btc = ws + OFF_BASTC + l0 + p0;
    const float* bts = ws + OFF_BASTS + l0 + p0;
    const float* omc = ws + OFF_OMCT + (long)b * 4096 + c0;
    const float* oms = ws + OFF_OMST + (long)b * 4096 + c0;
    for (int k = 0; k < 32; k++) {
        float4 bc = *(const float4*)&btc[k * 8192];
        float4 bsn = *(const float4*)&bts[k * 8192];
        float4 oc0 = *(const float4*)&omc[k * 128];
        float4 oc1 = *(const float4*)&omc[k * 128 + 4];
        float4 os0 = *(const float4*)&oms[k * 128];
        float4 os1 = *(const float4*)&oms[k * 128 + 4];
        float cv[4] = {bc.x, bc.y, bc.z, bc.w};
        float sv[4] = {bsn.x, bsn.y, bsn.z, bsn.w};
        float oc[8] = {oc0.x, oc0.y, oc0.z, oc0.w, oc1.x, oc1.y, oc1.z, oc1.w};
        float os[8] = {os0.x, os0.y, os0.z, os0.w, os1.x, os1.y, os1.z, os1.w};
        #pragma unroll
        for (int i = 0; i < 8; i++)
            #pragma unroll
            for (int p = 0; p < 4; p++)
                acc[i][p] = fmaf(oc[i], cv[p], fmaf(os[i], sv[p], acc[i][p]));
    }
    // 1x1 conv bypass: w[i=j][o], K-major in native conv_w layout
    const float* cwt = cw + (long)layer * 16384 + c0;
    for (int j = 0; j < 128; j++) {
        float4 hv = *(const float4*)&hx[j * 68 + p0];
        float4 w0 = *(const float4*)&cwt[j * 128];
        float4 w1 = *(const float4*)&cwt[j * 128 + 4];
        float hvv[4] = {hv.x, hv.y, hv.z, hv.w};
        float wv[8] = {w0.x, w0.y, w0.z, w0.w, w1.x, w1.y, w1.z, w1.w};
        #pragma unroll
        for (int i = 0; i < 8; i++)
            #pragma unroll
            for (int p = 0; p < 4; p++)
                acc[i][p] = fmaf(hvv[p], wv[i], acc[i][p]);
    }
    // bias + gelu; keep x_fno in regs, also publish to LDS (h tile is dead)
    float xfr[8][4];
    #pragma unroll
    for (int i = 0; i < 8; i++) {
        float bias = cb[layer * 128 + c0 + i];
        #pragma unroll
        for (int p = 0; p < 4; p++) xfr[i][p] = gelu_f(acc[i][p] + bias);
    }
    __syncthreads();   // all conv reads of h done
    #pragma unroll
    for (int i = 0; i < 8; i++)
        *(float4*)&hx[(c0 + i) * 68 + p0] =
            make_float4(xfr[i][0], xfr[i][1], xfr[i][2], xfr[i][3]);
    __syncthreads();

    // gate GEMM over x_fno (gw rows 0..127 are the x_fno half; x_cft half is in CG)
    const float* gwl = gw + (long)layer * 32768 + c0;
    float gac[8][4] = {};
    for (int c = 0; c < 128; c++) {
        float4 xv = *(const float4*)&hx[c * 68 + p0];
        float4 w0 = *(const float4*)&gwl[c * 128];
        float4 w1 = *(const float4*)&gwl[c * 128 + 4];
        float xvv[4] = {xv.x, xv.y, xv.z, xv.w};
        float wv[8] = {w0.x, w0.y, w0.z, w0.w, w1.x, w1.y, w1.z, w1.w};
        #pragma unroll
        for (int i = 0; i < 8; i++)
            #pragma unroll
            for (int p = 0; p < 4; p++)
                gac[i][p] = fmaf(xvv[p], wv[i], gac[i][p]);
    }
    // epilogue: sigmoid gate, h update, seg min/max
    float mnv = 1e30f, mxv = -1e30f;
    const float* cg = ws + OFF_CG + (long)(b * 4 + seg) * 128 + c0;
    #pragma unroll
    for (int i = 0; i < 8; i++) {
        float cgv = cg[i];
        float rv = ws[OFF_REC + (long)(b * 128 + c0 + i) * 4 + seg];
        float v[4];
        #pragma unroll
        for (int p = 0; p < 4; p++) {
            float gg = sigmoid_f(gac[i][p] + cgv);
            v[p] = xfr[i][p] + gg * rv;
            mnv = fminf(mnv, v[p]); mxv = fmaxf(mxv, v[p]);
        }
        *(float4*)&hb[(long)(c0 + i) * 8192 + l0 + p0] = make_float4(v[0], v[1], v[2], v[3]);
    }
    for (int off = 32; off; off >>= 1) {
        mnv = fminf(mnv, __shfl_down(mnv, off));
        mxv = fmaxf(mxv, __shfl_down(mxv, off));
    }
    if ((t & 63) == 0) { rmn[t >> 6] = mnv; rmx[t >> 6] = mxv; }
    __syncthreads();
    if (t == 0) {
        for (int w2 = 1; w2 < 4; w2++) { mnv = fminf(mnv, rmn[w2]); mxv = fmaxf(mxv, rmx[w2]); }
        unsigned int* mm = (unsigned int*)(ws + OFF_MNMX);
        atomicMin(&mm[seg], enc_f(mnv));
        atomicMax(&mm[4 + seg], enc_f(mxv));
    }
}

// ---------------- final fc1(gelu) + fc2 ----------------
__global__ __launch_bounds__(256, 4) void k_fc12(float* ws, const float* __restrict__ f1w,
                                                 const float* __restrict__ f1b,
                                                 const float* __restrict__ f2w,
                                                 const float* __restrict__ f2b,
                                                 float* __restrict__ out) {
    __shared__ float hx[128 * 68];
    int bid = blockIdx.x;
    int b = bid >> 7;
    int l0 = (bid & 127) * 64;
    int t = threadIdx.x;
    const float* hb = ws + OFF_H + (long)b * 1048576;
    #pragma unroll
    for (int i = 0; i < 8; i++) {
        int idx = t + i * 256;
        int row = idx >> 4, c4 = (idx & 15) * 4;
        *(float4*)&hx[row * 68 + c4] = *(const float4*)&hb[(long)row * 8192 + l0 + c4];
    }
    __syncthreads();
    int g = t >> 4, m = t & 15;
    int h0 = g * 8, p0 = m * 4;
    float acc[8][4] = {};
    const float* f1 = f1w + h0;
    for (int c = 0; c < 128; c++) {
        float4 hv = *(const float4*)&hx[c * 68 + p0];
        float4 w0 = *(const float4*)&f1[c * 128];
        float4 w1 = *(const float4*)&f1[c * 128 + 4];
        float hvv[4] = {hv.x, hv.y, hv.z, hv.w};
        float wv[8] = {w0.x, w0.y, w0.z, w0.w, w1.x, w1.y, w1.z, w1.w};
        #pragma unroll
        for (int i = 0; i < 8; i++)
            #pragma unroll
            for (int p = 0; p < 4; p++)
                acc[i][p] = fmaf(hvv[p], wv[i], acc[i][p]);
    }
    float outp[4] = {};
    #pragma unroll
    for (int i = 0; i < 8; i++) {
        float bias = f1b[h0 + i];
        float fw = f2w[h0 + i];
        #pragma unroll
        for (int p = 0; p < 4; p++)
            outp[p] = fmaf(fw, gelu_f(acc[i][p] + bias), outp[p]);
    }
    __syncthreads();   // done reading hx; reuse as reduction buffer [16 g][68]
    *(float4*)&hx[g * 68 + p0] = make_float4(outp[0], outp[1], outp[2], outp[3]);
    __syncthreads();
    if (t < 64) {
        float s = f2b[0];
        #pragma unroll
        for (int gg = 0; gg < 16; gg++) s += hx[gg * 68 + t];
        out[(long)b * 8192 + l0 + t] = s;
    }
}

extern "C" void kernel_launch(void* const* d_in, const int* in_sizes, int n_in,
                              void* d_out, int out_size, void* d_ws, size_t ws_size,
                              hipStream_t stream) {
    const float* x     = (const float*)d_in[0];
    const float* fc0_w = (const float*)d_in[1];
    const float* fc0_b = (const float*)d_in[2];
    const float* swr   = (const float*)d_in[3];
    const float* swi   = (const float*)d_in[4];
    const float* cw    = (const float*)d_in[5];
    const float* cb    = (const float*)d_in[6];
    const float* chw   = (const float*)d_in[7];
    const float* gw    = (const float*)d_in[8];
    const float* gb    = (const float*)d_in[9];
    const float* f1w   = (const float*)d_in[10];
    const float* f1b   = (const float*)d_in[11];
    const float* f2w   = (const float*)d_in[12];
    const float* f2b   = (const float*)d_in[13];
    float* ws = (float*)d_ws;
    float* out = (float*)d_out;

    k_tab<<<32, 256, 0, stream>>>(ws);
    k_init2<<<2112, 256, 0, stream>>>(ws, chw);
    k_fc0<<<256, 256, 0, stream>>>(ws, x, fc0_w, fc0_b);
    for (int layer = 0; layer < 4; layer++) {
        k_dft<<<dim3(16, 16), 256, 0, stream>>>(ws);
        k_cheb<<<1024, 256, 0, stream>>>(ws);
        k_b1<<<272, 256, 0, stream>>>(ws, layer);
        k_b2<<<144, 256, 0, stream>>>(ws, swr, swi, gw, gb, layer);
        k_fuse<<<1024, 256, 0, stream>>>(ws, cw, cb, gw, layer);
    }
    k_fc12<<<1024, 256, 0, stream>>>(ws, f1w, f1b, f2w, f2b, out);
}